// Round 1
// baseline (833.507 us; speedup 1.0000x reference)
//
#include <hip/hip_runtime.h>
#include <hip/hip_bf16.h>

typedef __attribute__((ext_vector_type(8))) __bf16 bf16x8;
typedef __attribute__((ext_vector_type(4))) __bf16 bf16x4;
typedef __attribute__((ext_vector_type(4))) float f32x4;

#define MFMA16(a, b, c) __builtin_amdgcn_mfma_f32_16x16x32_bf16((a), (b), (c), 0, 0, 0)

// B=2, S=2048, D=1024, H=16, DK=64
#define SEQ 2048
#define DIM 1024

// ---------------------------------------------------------------------------
// QKV projection: C[m,n] = sum_k A[m,k] * W[n,k] + bias[n], stored bf16.
// M=4096, N=1024, K=1024. 128x128 tile, BK=32, 256 threads (4 waves, 2x2 of
// 64x64 per wave). A/W are fp32 in global; converted to bf16 during staging.
// LDS rows padded 32->40 elems (80 B stride -> 2-way bank aliasing, free).
// ---------------------------------------------------------------------------
__global__ __launch_bounds__(256) void qkv_gemm(
    const float* __restrict__ qI, const float* __restrict__ kI, const float* __restrict__ vI,
    const float* __restrict__ wqI, const float* __restrict__ wkI, const float* __restrict__ wvI,
    const float* __restrict__ bqI, const float* __restrict__ bkI, const float* __restrict__ bvI,
    __bf16* __restrict__ Qp, __bf16* __restrict__ Kp, __bf16* __restrict__ Vp) {
  const int N = 1024, K = 1024;
  int z = blockIdx.z;
  const float* A = (z == 0) ? qI : (z == 1) ? kI : vI;
  const float* W = (z == 0) ? wqI : (z == 1) ? wkI : wvI;
  const float* bias = (z == 0) ? bqI : (z == 1) ? bkI : bvI;
  __bf16* C = (z == 0) ? Qp : (z == 1) ? Kp : Vp;

  __shared__ __bf16 As[128][40];
  __shared__ __bf16 Bs[128][40];

  int tid = threadIdx.x;
  int wave = tid >> 6, lane = tid & 63;
  int quad = lane >> 4, l16 = lane & 15;
  int wm = (wave >> 1) * 64, wn = (wave & 1) * 64;
  int m0 = blockIdx.y * 128, n0 = blockIdx.x * 128;
  int sr = tid >> 3;          // 0..31
  int sc = (tid & 7) * 4;     // 0,4,..,28

  f32x4 acc[4][4] = {};

  for (int k0 = 0; k0 < K; k0 += 32) {
    __syncthreads();
#pragma unroll
    for (int i = 0; i < 4; i++) {
      int r = sr + i * 32;
      float4 av = *(const float4*)&A[(size_t)(m0 + r) * K + k0 + sc];
      float4 wv4 = *(const float4*)&W[(size_t)(n0 + r) * K + k0 + sc];
      bf16x4 ah = {(__bf16)av.x, (__bf16)av.y, (__bf16)av.z, (__bf16)av.w};
      bf16x4 wh = {(__bf16)wv4.x, (__bf16)wv4.y, (__bf16)wv4.z, (__bf16)wv4.w};
      *(bf16x4*)&As[r][sc] = ah;
      *(bf16x4*)&Bs[r][sc] = wh;
    }
    __syncthreads();
    bf16x8 af[4], bfv[4];
#pragma unroll
    for (int i = 0; i < 4; i++) af[i] = *(bf16x8*)&As[wm + i * 16 + l16][quad * 8];
#pragma unroll
    for (int j = 0; j < 4; j++) bfv[j] = *(bf16x8*)&Bs[wn + j * 16 + l16][quad * 8];
#pragma unroll
    for (int i = 0; i < 4; i++)
#pragma unroll
      for (int j = 0; j < 4; j++) acc[i][j] = MFMA16(af[i], bfv[j], acc[i][j]);
  }

#pragma unroll
  for (int j = 0; j < 4; j++) {
    int col = n0 + wn + j * 16 + l16;
    float bj = bias[col];
#pragma unroll
    for (int i = 0; i < 4; i++)
#pragma unroll
      for (int r = 0; r < 4; r++) {
        int row = m0 + wm + i * 16 + quad * 4 + r;
        C[(size_t)row * N + col] = (__bf16)(acc[i][j][r] + bj);
      }
  }
}

// ---------------------------------------------------------------------------
// Output projection: x[m,n] = sum_k Oc[m,k]*wo[n,k] + bo[n], fp32 out.
// ---------------------------------------------------------------------------
__global__ __launch_bounds__(256) void out_gemm(
    const __bf16* __restrict__ A, const float* __restrict__ W,
    const float* __restrict__ bias, float* __restrict__ C) {
  const int N = 1024, K = 1024;
  __shared__ __bf16 As[128][40];
  __shared__ __bf16 Bs[128][40];

  int tid = threadIdx.x;
  int wave = tid >> 6, lane = tid & 63;
  int quad = lane >> 4, l16 = lane & 15;
  int wm = (wave >> 1) * 64, wn = (wave & 1) * 64;
  int m0 = blockIdx.y * 128, n0 = blockIdx.x * 128;
  int sr = tid >> 3;
  int sc = (tid & 7) * 4;

  f32x4 acc[4][4] = {};

  for (int k0 = 0; k0 < K; k0 += 32) {
    __syncthreads();
#pragma unroll
    for (int i = 0; i < 4; i++) {
      int r = sr + i * 32;
      bf16x4 ah = *(const bf16x4*)&A[(size_t)(m0 + r) * K + k0 + sc];
      float4 wv4 = *(const float4*)&W[(size_t)(n0 + r) * K + k0 + sc];
      bf16x4 wh = {(__bf16)wv4.x, (__bf16)wv4.y, (__bf16)wv4.z, (__bf16)wv4.w};
      *(bf16x4*)&As[r][sc] = ah;
      *(bf16x4*)&Bs[r][sc] = wh;
    }
    __syncthreads();
    bf16x8 af[4], bfv[4];
#pragma unroll
    for (int i = 0; i < 4; i++) af[i] = *(bf16x8*)&As[wm + i * 16 + l16][quad * 8];
#pragma unroll
    for (int j = 0; j < 4; j++) bfv[j] = *(bf16x8*)&Bs[wn + j * 16 + l16][quad * 8];
#pragma unroll
    for (int i = 0; i < 4; i++)
#pragma unroll
      for (int j = 0; j < 4; j++) acc[i][j] = MFMA16(af[i], bfv[j], acc[i][j]);
  }

#pragma unroll
  for (int j = 0; j < 4; j++) {
    int col = n0 + wn + j * 16 + l16;
    float bj = bias[col];
#pragma unroll
    for (int i = 0; i < 4; i++)
#pragma unroll
      for (int r = 0; r < 4; r++) {
        int row = m0 + wm + i * 16 + quad * 4 + r;
        C[(size_t)row * N + col] = acc[i][j][r] + bj;
      }
  }
}

// ---------------------------------------------------------------------------
// Fused causal attention for one (b,h,q-tile of 64 rows).
// Pass 1: online row max/sum over K-tiles of 128 (QK^T recompute-style flash).
// Pass 2: recompute scores, write normalized P (fp32, exact 0 in masked
// region) to the attn output, and accumulate O = P*V via LDS round-trip
// (P: C-layout -> bf16 LDS -> A-frags; V staged transposed for B-frags).
// Block = 256 threads (4 waves); wave w owns rows q0+16w..q0+16w+15.
// ---------------------------------------------------------------------------
__global__ __launch_bounds__(256) void attn_fused(
    const __bf16* __restrict__ Qp, const __bf16* __restrict__ Kp,
    const __bf16* __restrict__ Vp, float* __restrict__ attn,
    __bf16* __restrict__ Oc) {
  int bh = blockIdx.y;
  int b = bh >> 4;
  int hofs = (bh & 15) * 64;
  int q0 = blockIdx.x * 64;

  int tid = threadIdx.x;
  int wave = tid >> 6, lane = tid & 63;
  int quad = lane >> 4, l16 = lane & 15;

  __shared__ __bf16 Qs[64][72];     // pad 64->72: 144 B row stride (16B-aligned)
  __shared__ __bf16 Ks[128][72];
  __shared__ __bf16 Vts[64][136];   // V transposed [d][k], pad 128->136
  __shared__ __bf16 Ps[64][136];    // P tile [q][k] bf16

  const size_t rowbase = (size_t)b * SEQ;

  // stage Q tile (64x64)
#pragma unroll
  for (int it = 0; it < 2; it++) {
    int flat = tid * 8 + it * 2048;
    int r = flat >> 6, c = flat & 63;
    bf16x8 qv = *(const bf16x8*)&Qp[(rowbase + q0 + r) * DIM + hofs + c];
    *(bf16x8*)&Qs[r][c] = qv;
  }

  int myrow = q0 + wave * 16 + quad * 4;  // +r
  float m_i[4], l_i[4];
#pragma unroll
  for (int r = 0; r < 4; r++) { m_i[r] = -1e30f; l_i[r] = 0.f; }

  int ktmax = (q0 + 63) >> 7;  // last K-tile with any valid (causal) column

  // ---------------- pass 1: row stats ----------------
  for (int kt = 0; kt <= ktmax; kt++) {
    int k0 = kt << 7;
    __syncthreads();
#pragma unroll
    for (int it = 0; it < 4; it++) {
      int flat = tid * 8 + it * 2048;
      int r = flat >> 6, c = flat & 63;
      bf16x8 kv = *(const bf16x8*)&Kp[(rowbase + k0 + r) * DIM + hofs + c];
      *(bf16x8*)&Ks[r][c] = kv;
    }
    __syncthreads();

    f32x4 sacc[8] = {};
#pragma unroll
    for (int ks = 0; ks < 2; ks++) {
      bf16x8 a = *(bf16x8*)&Qs[wave * 16 + l16][ks * 32 + quad * 8];
#pragma unroll
      for (int t = 0; t < 8; t++) {
        bf16x8 bb = *(bf16x8*)&Ks[t * 16 + l16][ks * 32 + quad * 8];
        sacc[t] = MFMA16(a, bb, sacc[t]);
      }
    }
#pragma unroll
    for (int r = 0; r < 4; r++) {
      int rowr = myrow + r;
      float sv[8];
      float mx = -1e30f;
#pragma unroll
      for (int t = 0; t < 8; t++) {
        float s = sacc[t][r] * 0.125f;
        int col = k0 + t * 16 + l16;
        if (col > rowr) s = -1e30f;
        sv[t] = s;
        mx = fmaxf(mx, s);
      }
#pragma unroll
      for (int off = 1; off < 16; off <<= 1) mx = fmaxf(mx, __shfl_xor(mx, off));
      float mn = fmaxf(m_i[r], mx);
      float sum = 0.f;
#pragma unroll
      for (int t = 0; t < 8; t++) sum += __expf(sv[t] - mn);
#pragma unroll
      for (int off = 1; off < 16; off <<= 1) sum += __shfl_xor(sum, off);
      l_i[r] = l_i[r] * __expf(m_i[r] - mn) + sum;
      m_i[r] = mn;
    }
  }

  float rl[4];
#pragma unroll
  for (int r = 0; r < 4; r++) rl[r] = 1.f / l_i[r];

  f32x4 oacc[4] = {};
  float* attn_bh = attn + (size_t)bh * SEQ * SEQ;

  // ---------------- pass 2: P write + O accumulate ----------------
  for (int kt = 0; kt < SEQ / 128; kt++) {
    int k0 = kt << 7;
    if (kt <= ktmax) {
      __syncthreads();
#pragma unroll
      for (int it = 0; it < 4; it++) {
        int flat = tid * 8 + it * 2048;
        int r = flat >> 6, c = flat & 63;
        bf16x8 kv = *(const bf16x8*)&Kp[(rowbase + k0 + r) * DIM + hofs + c];
        *(bf16x8*)&Ks[r][c] = kv;
        bf16x8 vv = *(const bf16x8*)&Vp[(rowbase + k0 + r) * DIM + hofs + c];
#pragma unroll
        for (int j = 0; j < 8; j++) Vts[c + j][r] = vv[j];  // transpose into [d][k]
      }
      __syncthreads();

      f32x4 sacc[8] = {};
#pragma unroll
      for (int ks = 0; ks < 2; ks++) {
        bf16x8 a = *(bf16x8*)&Qs[wave * 16 + l16][ks * 32 + quad * 8];
#pragma unroll
        for (int t = 0; t < 8; t++) {
          bf16x8 bb = *(bf16x8*)&Ks[t * 16 + l16][ks * 32 + quad * 8];
          sacc[t] = MFMA16(a, bb, sacc[t]);
        }
      }
#pragma unroll
      for (int r = 0; r < 4; r++) {
        int rowr = myrow + r;
        size_t arow = (size_t)rowr * SEQ;
#pragma unroll
        for (int t = 0; t < 8; t++) {
          int col = k0 + t * 16 + l16;
          float s = sacc[t][r] * 0.125f;
          float p = (col <= rowr) ? __expf(s - m_i[r]) * rl[r] : 0.f;
          attn_bh[arow + col] = p;
          Ps[wave * 16 + quad * 4 + r][t * 16 + l16] = (__bf16)p;
        }
      }
      __syncthreads();
#pragma unroll
      for (int ks = 0; ks < 4; ks++) {
        bf16x8 a = *(bf16x8*)&Ps[wave * 16 + l16][ks * 32 + quad * 8];
#pragma unroll
        for (int dt = 0; dt < 4; dt++) {
          bf16x8 bb = *(bf16x8*)&Vts[dt * 16 + l16][ks * 32 + quad * 8];
          oacc[dt] = MFMA16(a, bb, oacc[dt]);
        }
      }
    } else {
      // fully-masked tile: write exact zeros (reference softmax underflows to 0)
      float4 z4 = make_float4(0.f, 0.f, 0.f, 0.f);
#pragma unroll
      for (int i = 0; i < 8; i++) {
        int f4 = tid + i * 256;     // 0..2047 over 64x32 float4s
        int r = f4 >> 5;
        int c = (f4 & 31) * 4;
        *(float4*)&attn_bh[(size_t)(q0 + r) * SEQ + k0 + c] = z4;
      }
    }
  }

  // write O strip (bf16) for the final projection
#pragma unroll
  for (int dt = 0; dt < 4; dt++)
#pragma unroll
    for (int r = 0; r < 4; r++) {
      int row = myrow + r;
      int col = hofs + dt * 16 + l16;
      Oc[(rowbase + row) * DIM + col] = (__bf16)oacc[dt][r];
    }
}

// ---------------------------------------------------------------------------
extern "C" void kernel_launch(void* const* d_in, const int* in_sizes, int n_in,
                              void* d_out, int out_size, void* d_ws, size_t ws_size,
                              hipStream_t stream) {
  const float* q = (const float*)d_in[0];
  const float* k = (const float*)d_in[1];
  const float* v = (const float*)d_in[2];
  // d_in[3] = causal mask (tril) — implemented analytically in attn_fused
  const float* wq = (const float*)d_in[4];
  const float* bq = (const float*)d_in[5];
  const float* wk = (const float*)d_in[6];
  const float* bk = (const float*)d_in[7];
  const float* wv = (const float*)d_in[8];
  const float* bv = (const float*)d_in[9];
  const float* wo = (const float*)d_in[10];
  const float* bo = (const float*)d_in[11];

  float* xout = (float*)d_out;                       // [2,2048,1024]
  float* attn = xout + (size_t)2 * SEQ * DIM;        // [2,16,2048,2048]

  __bf16* Qp = (__bf16*)d_ws;                        // [2,2048,1024] bf16
  __bf16* Kp = Qp + (size_t)2 * SEQ * DIM;
  __bf16* Vp = Kp + (size_t)2 * SEQ * DIM;
  __bf16* Oc = Vp + (size_t)2 * SEQ * DIM;           // attention output, bf16

  dim3 blk(256);
  dim3 g1(8, 32, 3);   // N-tiles x M-tiles x {Q,K,V}
  qkv_gemm<<<g1, blk, 0, stream>>>(q, k, v, wq, wk, wv, bq, bk, bv, Qp, Kp, Vp);

  dim3 g2(32, 32);     // q-tiles x (B*H)
  attn_fused<<<g2, blk, 0, stream>>>(Qp, Kp, Vp, attn, Oc);

  dim3 g3(8, 32);
  out_gemm<<<g3, blk, 0, stream>>>(Oc, wo, bo, xout);
}

// Round 2
// 793.345 us; speedup vs baseline: 1.0506x; 1.0506x over previous
//
#include <hip/hip_runtime.h>
#include <hip/hip_bf16.h>

typedef __attribute__((ext_vector_type(8))) __bf16 bf16x8;
typedef __attribute__((ext_vector_type(4))) __bf16 bf16x4;
typedef __attribute__((ext_vector_type(4))) float f32x4;

#define MFMA16(a, b, c) __builtin_amdgcn_mfma_f32_16x16x32_bf16((a), (b), (c), 0, 0, 0)

// B=2, S=2048, D=1024, H=16, DK=64
#define SEQ 2048
#define DIM 1024

// ---------------------------------------------------------------------------
// QKV projection: C[m,n] = sum_k A[m,k] * W[n,k] + bias[n].
// z==0 (Q): output pre-scaled by 0.125 (1/sqrt(DK)), layout [b,s,dim] bf16.
// z==1 (K): layout [b,s,dim] bf16.
// z==2 (V): stored TRANSPOSED as Vt[bh][dk][s] (bh=b*16+h) so the attention
//           kernel can stage V^T with vectorized loads (no LDS transpose).
// Register double-buffer on the global fp32 loads hides staging latency.
// ---------------------------------------------------------------------------
__global__ __launch_bounds__(256) void qkv_gemm(
    const float* __restrict__ qI, const float* __restrict__ kI, const float* __restrict__ vI,
    const float* __restrict__ wqI, const float* __restrict__ wkI, const float* __restrict__ wvI,
    const float* __restrict__ bqI, const float* __restrict__ bkI, const float* __restrict__ bvI,
    __bf16* __restrict__ Qp, __bf16* __restrict__ Kp, __bf16* __restrict__ Vt) {
  const int N = 1024, K = 1024;
  int z = blockIdx.z;
  const float* A = (z == 0) ? qI : (z == 1) ? kI : vI;
  const float* W = (z == 0) ? wqI : (z == 1) ? wkI : wvI;
  const float* bias = (z == 0) ? bqI : (z == 1) ? bkI : bvI;

  __shared__ __bf16 As[128][40];
  __shared__ __bf16 Bs[128][40];

  int tid = threadIdx.x;
  int wave = tid >> 6, lane = tid & 63;
  int quad = lane >> 4, l16 = lane & 15;
  int wm = (wave >> 1) * 64, wn = (wave & 1) * 64;
  int m0 = blockIdx.y * 128, n0 = blockIdx.x * 128;
  int sr = tid >> 3;          // 0..31
  int sc = (tid & 7) * 4;     // 0,4,..,28

  f32x4 acc[4][4] = {};

  float4 pa[4], pw[4];
#pragma unroll
  for (int i = 0; i < 4; i++) {
    int r = sr + i * 32;
    pa[i] = *(const float4*)&A[(size_t)(m0 + r) * K + sc];
    pw[i] = *(const float4*)&W[(size_t)(n0 + r) * K + sc];
  }

  for (int k0 = 0; k0 < K; k0 += 32) {
    __syncthreads();
#pragma unroll
    for (int i = 0; i < 4; i++) {
      int r = sr + i * 32;
      bf16x4 ah = {(__bf16)pa[i].x, (__bf16)pa[i].y, (__bf16)pa[i].z, (__bf16)pa[i].w};
      bf16x4 wh = {(__bf16)pw[i].x, (__bf16)pw[i].y, (__bf16)pw[i].z, (__bf16)pw[i].w};
      *(bf16x4*)&As[r][sc] = ah;
      *(bf16x4*)&Bs[r][sc] = wh;
    }
    __syncthreads();
    if (k0 + 32 < K) {
#pragma unroll
      for (int i = 0; i < 4; i++) {
        int r = sr + i * 32;
        pa[i] = *(const float4*)&A[(size_t)(m0 + r) * K + k0 + 32 + sc];
        pw[i] = *(const float4*)&W[(size_t)(n0 + r) * K + k0 + 32 + sc];
      }
    }
    bf16x8 af[4], bfv[4];
#pragma unroll
    for (int i = 0; i < 4; i++) af[i] = *(bf16x8*)&As[wm + i * 16 + l16][quad * 8];
#pragma unroll
    for (int j = 0; j < 4; j++) bfv[j] = *(bf16x8*)&Bs[wn + j * 16 + l16][quad * 8];
#pragma unroll
    for (int i = 0; i < 4; i++)
#pragma unroll
      for (int j = 0; j < 4; j++) acc[i][j] = MFMA16(af[i], bfv[j], acc[i][j]);
  }

#pragma unroll
  for (int j = 0; j < 4; j++) {
    int col = n0 + wn + j * 16 + l16;
    float bj = bias[col];
    if (z == 2) {
      // transposed store: Vt[(bh*64+dk)*2048 + s], 4 consecutive s per lane
#pragma unroll
      for (int i = 0; i < 4; i++) {
        int row0 = m0 + wm + i * 16 + quad * 4;
        int bb = row0 >> 11, s = row0 & 2047;
        bf16x4 pv = {(__bf16)(acc[i][j][0] + bj), (__bf16)(acc[i][j][1] + bj),
                     (__bf16)(acc[i][j][2] + bj), (__bf16)(acc[i][j][3] + bj)};
        *(bf16x4*)&Vt[((size_t)bb * 1024 + col) * SEQ + s] = pv;
      }
    } else {
      __bf16* C = (z == 0) ? Qp : Kp;
      float scale = (z == 0) ? 0.125f : 1.0f;
#pragma unroll
      for (int i = 0; i < 4; i++)
#pragma unroll
        for (int r = 0; r < 4; r++) {
          int row = m0 + wm + i * 16 + quad * 4 + r;
          C[(size_t)row * N + col] = (__bf16)((acc[i][j][r] + bj) * scale);
        }
    }
  }
}

// ---------------------------------------------------------------------------
// Output projection: x[m,n] = sum_k Oc[m,k]*wo[n,k] + bo[n], fp32 out.
// ---------------------------------------------------------------------------
__global__ __launch_bounds__(256) void out_gemm(
    const __bf16* __restrict__ A, const float* __restrict__ W,
    const float* __restrict__ bias, float* __restrict__ C) {
  const int N = 1024, K = 1024;
  __shared__ __bf16 As[128][40];
  __shared__ __bf16 Bs[128][40];

  int tid = threadIdx.x;
  int wave = tid >> 6, lane = tid & 63;
  int quad = lane >> 4, l16 = lane & 15;
  int wm = (wave >> 1) * 64, wn = (wave & 1) * 64;
  int m0 = blockIdx.y * 128, n0 = blockIdx.x * 128;
  int sr = tid >> 3;
  int sc = (tid & 7) * 4;

  f32x4 acc[4][4] = {};

  bf16x4 pa[4];
  float4 pw[4];
#pragma unroll
  for (int i = 0; i < 4; i++) {
    int r = sr + i * 32;
    pa[i] = *(const bf16x4*)&A[(size_t)(m0 + r) * K + sc];
    pw[i] = *(const float4*)&W[(size_t)(n0 + r) * K + sc];
  }

  for (int k0 = 0; k0 < K; k0 += 32) {
    __syncthreads();
#pragma unroll
    for (int i = 0; i < 4; i++) {
      int r = sr + i * 32;
      bf16x4 wh = {(__bf16)pw[i].x, (__bf16)pw[i].y, (__bf16)pw[i].z, (__bf16)pw[i].w};
      *(bf16x4*)&As[r][sc] = pa[i];
      *(bf16x4*)&Bs[r][sc] = wh;
    }
    __syncthreads();
    if (k0 + 32 < K) {
#pragma unroll
      for (int i = 0; i < 4; i++) {
        int r = sr + i * 32;
        pa[i] = *(const bf16x4*)&A[(size_t)(m0 + r) * K + k0 + 32 + sc];
        pw[i] = *(const float4*)&W[(size_t)(n0 + r) * K + k0 + 32 + sc];
      }
    }
    bf16x8 af[4], bfv[4];
#pragma unroll
    for (int i = 0; i < 4; i++) af[i] = *(bf16x8*)&As[wm + i * 16 + l16][quad * 8];
#pragma unroll
    for (int j = 0; j < 4; j++) bfv[j] = *(bf16x8*)&Bs[wn + j * 16 + l16][quad * 8];
#pragma unroll
    for (int i = 0; i < 4; i++)
#pragma unroll
      for (int j = 0; j < 4; j++) acc[i][j] = MFMA16(af[i], bfv[j], acc[i][j]);
  }

#pragma unroll
  for (int j = 0; j < 4; j++) {
    int col = n0 + wn + j * 16 + l16;
    float bj = bias[col];
#pragma unroll
    for (int i = 0; i < 4; i++)
#pragma unroll
      for (int r = 0; r < 4; r++) {
        int row = m0 + wm + i * 16 + quad * 4 + r;
        C[(size_t)row * N + col] = acc[i][j][r] + bj;
      }
  }
}

// ---------------------------------------------------------------------------
// Fused causal attention, S^T orientation.
// QK^T computed as S^T = K·Q^T: A-frags from K, B-frags from Q. C-layout then
// gives lane (quad,l16): q = l16 (wave-local), k = t*16 + quad*4 + r — four
// CONSECUTIVE k per lane => float4 attn stores, bf16x4 Ps writes, and the
// softmax row-reduce is just shfl_xor(16)+shfl_xor(32) across quads.
// V arrives pre-transposed (Vt[bh][dk][s]) => vectorized staging, no LDS
// transpose. Q is pre-scaled by 1/8 in the projection.
// Block = 256 threads (4 waves); wave w owns q rows q0+16w .. q0+16w+15.
// ---------------------------------------------------------------------------
__global__ __launch_bounds__(256) void attn_fused(
    const __bf16* __restrict__ Qp, const __bf16* __restrict__ Kp,
    const __bf16* __restrict__ Vt, float* __restrict__ attn,
    __bf16* __restrict__ Oc) {
  int bh = blockIdx.y;
  int b = bh >> 4;
  int hofs = (bh & 15) * 64;
  int q0 = blockIdx.x * 64;

  int tid = threadIdx.x;
  int wave = tid >> 6, lane = tid & 63;
  int quad = lane >> 4, l16 = lane & 15;

  __shared__ __bf16 Qs[64][72];     // 144 B row stride (16B-aligned)
  __shared__ __bf16 Ks[128][72];
  __shared__ __bf16 Vts[64][136];   // V^T tile [dk][k], staged directly
  __shared__ __bf16 Ps[64][136];    // P tile [q][k] bf16

  const size_t rowbase = (size_t)b * SEQ;
  const size_t vtbase = (size_t)bh * 64 * SEQ;

  // stage Q tile (64x64), already scaled by 1/8
#pragma unroll
  for (int it = 0; it < 2; it++) {
    int flat = tid * 8 + it * 2048;
    int r = flat >> 6, c = flat & 63;
    *(bf16x8*)&Qs[r][c] = *(const bf16x8*)&Qp[(rowbase + q0 + r) * DIM + hofs + c];
  }
  __syncthreads();

  int qg = q0 + wave * 16 + l16;   // this lane's q row
  // loop-invariant Q B-fragments (DK=64 -> two k-halves)
  bf16x8 qfrag0 = *(bf16x8*)&Qs[wave * 16 + l16][quad * 8];
  bf16x8 qfrag1 = *(bf16x8*)&Qs[wave * 16 + l16][32 + quad * 8];

  float m_i = -1e30f, l_i = 0.f;
  int ktmax = (q0 + 63) >> 7;

  // ---------------- pass 1: row stats ----------------
  for (int kt = 0; kt <= ktmax; kt++) {
    int k0 = kt << 7;
    __syncthreads();
#pragma unroll
    for (int it = 0; it < 4; it++) {
      int flat = tid * 8 + it * 2048;
      int r = flat >> 6, c = flat & 63;
      *(bf16x8*)&Ks[r][c] = *(const bf16x8*)&Kp[(rowbase + k0 + r) * DIM + hofs + c];
    }
    __syncthreads();

    f32x4 sacc[8] = {};
#pragma unroll
    for (int t = 0; t < 8; t++) {
      bf16x8 a0 = *(bf16x8*)&Ks[t * 16 + l16][quad * 8];
      bf16x8 a1 = *(bf16x8*)&Ks[t * 16 + l16][32 + quad * 8];
      sacc[t] = MFMA16(a0, qfrag0, sacc[t]);
      sacc[t] = MFMA16(a1, qfrag1, sacc[t]);
    }

    bool diag = (kt == ktmax);
    float sv[32];
    float mx = -1e30f;
#pragma unroll
    for (int t = 0; t < 8; t++)
#pragma unroll
      for (int r = 0; r < 4; r++) {
        float s = sacc[t][r];
        int k = k0 + t * 16 + quad * 4 + r;
        if (diag && k > qg) s = -1e30f;
        sv[t * 4 + r] = s;
        mx = fmaxf(mx, s);
      }
    mx = fmaxf(mx, __shfl_xor(mx, 16));
    mx = fmaxf(mx, __shfl_xor(mx, 32));
    float mn = fmaxf(m_i, mx);
    float sum = 0.f;
#pragma unroll
    for (int i = 0; i < 32; i++) sum += __expf(sv[i] - mn);
    sum += __shfl_xor(sum, 16);
    sum += __shfl_xor(sum, 32);
    l_i = l_i * __expf(m_i - mn) + sum;
    m_i = mn;
  }

  float rl = 1.f / l_i;
  f32x4 oacc[4] = {};
  float* attn_bh = attn + (size_t)bh * SEQ * SEQ;
  float* attn_row = attn_bh + (size_t)qg * SEQ;

  // ---------------- pass 2: P write + O accumulate ----------------
  for (int kt = 0; kt < SEQ / 128; kt++) {
    int k0 = kt << 7;
    if (kt <= ktmax) {
      __syncthreads();
#pragma unroll
      for (int it = 0; it < 4; it++) {
        int flat = tid * 8 + it * 2048;
        int r = flat >> 6, c = flat & 63;
        *(bf16x8*)&Ks[r][c] = *(const bf16x8*)&Kp[(rowbase + k0 + r) * DIM + hofs + c];
        int d = flat >> 7, c2 = flat & 127;
        *(bf16x8*)&Vts[d][c2] = *(const bf16x8*)&Vt[vtbase + (size_t)d * SEQ + k0 + c2];
      }
      __syncthreads();

      f32x4 sacc[8] = {};
#pragma unroll
      for (int t = 0; t < 8; t++) {
        bf16x8 a0 = *(bf16x8*)&Ks[t * 16 + l16][quad * 8];
        bf16x8 a1 = *(bf16x8*)&Ks[t * 16 + l16][32 + quad * 8];
        sacc[t] = MFMA16(a0, qfrag0, sacc[t]);
        sacc[t] = MFMA16(a1, qfrag1, sacc[t]);
      }

      bool diag = (kt == ktmax);
#pragma unroll
      for (int t = 0; t < 8; t++) {
        float p[4];
#pragma unroll
        for (int r = 0; r < 4; r++) {
          int k = k0 + t * 16 + quad * 4 + r;
          float s = sacc[t][r];
          p[r] = (!diag || k <= qg) ? __expf(s - m_i) * rl : 0.f;
        }
        *(float4*)&attn_row[k0 + t * 16 + quad * 4] = make_float4(p[0], p[1], p[2], p[3]);
        bf16x4 ph = {(__bf16)p[0], (__bf16)p[1], (__bf16)p[2], (__bf16)p[3]};
        *(bf16x4*)&Ps[wave * 16 + l16][t * 16 + quad * 4] = ph;
      }
      __syncthreads();   // Ps cross-lane visibility

#pragma unroll
      for (int ks = 0; ks < 4; ks++) {
        bf16x8 a = *(bf16x8*)&Ps[wave * 16 + l16][ks * 32 + quad * 8];
#pragma unroll
        for (int dt = 0; dt < 4; dt++) {
          bf16x8 bb = *(bf16x8*)&Vts[dt * 16 + l16][ks * 32 + quad * 8];
          oacc[dt] = MFMA16(a, bb, oacc[dt]);
        }
      }
    } else {
      // fully-masked tile: write exact zeros
      float4 z4 = make_float4(0.f, 0.f, 0.f, 0.f);
#pragma unroll
      for (int i = 0; i < 8; i++) {
        int f4 = tid + i * 256;
        int r = f4 >> 5;
        int c = (f4 & 31) * 4;
        *(float4*)&attn_bh[(size_t)(q0 + r) * SEQ + k0 + c] = z4;
      }
    }
  }

  // write O strip (bf16): C-layout col=l16=dk, row=quad*4+rr=q-within-wave
#pragma unroll
  for (int dt = 0; dt < 4; dt++)
#pragma unroll
    for (int rr = 0; rr < 4; rr++) {
      int row = q0 + wave * 16 + quad * 4 + rr;
      Oc[(rowbase + row) * DIM + hofs + dt * 16 + l16] = (__bf16)oacc[dt][rr];
    }
}

// ---------------------------------------------------------------------------
extern "C" void kernel_launch(void* const* d_in, const int* in_sizes, int n_in,
                              void* d_out, int out_size, void* d_ws, size_t ws_size,
                              hipStream_t stream) {
  const float* q = (const float*)d_in[0];
  const float* k = (const float*)d_in[1];
  const float* v = (const float*)d_in[2];
  // d_in[3] = causal mask (tril) — analytic in attn_fused
  const float* wq = (const float*)d_in[4];
  const float* bq = (const float*)d_in[5];
  const float* wk = (const float*)d_in[6];
  const float* bk = (const float*)d_in[7];
  const float* wv = (const float*)d_in[8];
  const float* bv = (const float*)d_in[9];
  const float* wo = (const float*)d_in[10];
  const float* bo = (const float*)d_in[11];

  float* xout = (float*)d_out;                       // [2,2048,1024]
  float* attn = xout + (size_t)2 * SEQ * DIM;        // [2,16,2048,2048]

  __bf16* Qp = (__bf16*)d_ws;                        // [2,2048,1024] bf16, pre-scaled 1/8
  __bf16* Kp = Qp + (size_t)2 * SEQ * DIM;
  __bf16* Vt = Kp + (size_t)2 * SEQ * DIM;           // [32,64,2048] transposed V
  __bf16* Oc = Vt + (size_t)2 * SEQ * DIM;           // attention output, bf16

  dim3 blk(256);
  dim3 g1(8, 32, 3);
  qkv_gemm<<<g1, blk, 0, stream>>>(q, k, v, wq, wk, wv, bq, bk, bv, Qp, Kp, Vt);

  dim3 g2(32, 32);
  attn_fused<<<g2, blk, 0, stream>>>(Qp, Kp, Vt, attn, Oc);

  dim3 g3(8, 32);
  out_gemm<<<g3, blk, 0, stream>>>(Oc, wo, bo, xout);
}